// Round 2
// baseline (406.209 us; speedup 1.0000x reference)
//
#include <hip/hip_runtime.h>

#define PHI     1.618033988749895f
#define INV_PHI 0.6180339887498949f

__device__ __forceinline__ float phi_spiral(float v) {
    // sigmoid(v/phi) * (v*phi / (1+|v|))
    float e = __expf(-v * INV_PHI);
    float s = __fdividef(1.0f, 1.0f + e);
    float g = __fdividef(v * PHI, 1.0f + fabsf(v));
    return s * g;
}

#define LSTR 20   // floats per LDS row: multiple of 4 (16B-aligned b128), ~2-way bank alias

// Requires gridDim.x * 256 == B (B = 262144 -> 1024 blocks exactly).
__global__ __launch_bounds__(256, 4) void seven_neurons_kernel(
    const float* __restrict__ x,
    const float* __restrict__ W_in,  const float* __restrict__ b_in,
    const float* __restrict__ Wn,    const float* __restrict__ bn,
    const float* __restrict__ W_int, const float* __restrict__ b_int,
    const float* __restrict__ gamma, const float* __restrict__ beta,
    const float* __restrict__ W_out, const float* __restrict__ b_out,
    float* __restrict__ out)
{
    __shared__ float xt[256 * LSTR];          // 20 KB: 256 rows x 16-col chunk
    const int t    = threadIdx.x;
    const int row0 = blockIdx.x * 256;
    const int rr   = t >> 2;                  // staging row within wave-quad
    const int g    = t & 3;                   // staging 16B group

    // ---- stage 1: h = spiral(x @ W_in^T + b_in)   [256 -> 49]
    float h[49];
#pragma unroll
    for (int j = 0; j < 49; ++j) h[j] = b_in[j];     // uniform -> s_load

#pragma unroll 1
    for (int c0 = 0; c0 < 256; c0 += 16) {
        __syncthreads();                              // previous chunk's reads done
        // cooperative coalesced stage: 256x16 tile, 4 float4 per thread
#pragma unroll
        for (int q = 0; q < 4; ++q) {
            const int r = rr + q * 64;
            const float4 v = *reinterpret_cast<const float4*>(
                x + (size_t)(row0 + r) * 256 + c0 + g * 4);
            *reinterpret_cast<float4*>(&xt[r * LSTR + g * 4]) = v;
        }
        __syncthreads();

        float xv[16];
#pragma unroll
        for (int c = 0; c < 16; c += 4) {
            const float4 v = *reinterpret_cast<const float4*>(&xt[t * LSTR + c]);
            xv[c + 0] = v.x; xv[c + 1] = v.y; xv[c + 2] = v.z; xv[c + 3] = v.w;
        }
#pragma unroll
        for (int j = 0; j < 49; ++j) {
            const float* w = W_in + j * 256 + c0;    // wave-uniform -> scalar loads
            float acc = h[j];
#pragma unroll
            for (int u = 0; u < 16; ++u) acc = fmaf(xv[u], w[u], acc);
            h[j] = acc;
        }
    }
#pragma unroll
    for (int j = 0; j < 49; ++j) h[j] = phi_spiral(h[j]);

    // ---- stage 2: combined = spiral(einsum('bi,khi->bkh'))   [49 -> 49]
    float comb[49];
#pragma unroll 1
    for (int m = 0; m < 49; ++m) {
        const float* w = Wn + m * 49;
        float acc = bn[m];
#pragma unroll
        for (int i = 0; i < 49; ++i) acc = fmaf(h[i], w[i], acc);
        comb[m] = phi_spiral(acc);
    }

    // ---- stage 3: integrated = spiral(comb @ W_int^T + b_int)   [49 -> 21]
    float integ[21];
#pragma unroll 1
    for (int o = 0; o < 21; ++o) {
        const float* w = W_int + o * 49;
        float acc = b_int[o];
#pragma unroll
        for (int i = 0; i < 49; ++i) acc = fmaf(comb[i], w[i], acc);
        integ[o] = phi_spiral(acc);
    }

    // ---- LayerNorm over 21 (eps = 1e-5)
    float mu = 0.f;
#pragma unroll
    for (int o = 0; o < 21; ++o) mu += integ[o];
    mu *= (1.0f / 21.0f);
    float var = 0.f;
#pragma unroll
    for (int o = 0; o < 21; ++o) { float d = integ[o] - mu; var = fmaf(d, d, var); }
    var *= (1.0f / 21.0f);
    const float r = rsqrtf(var + 1e-5f);
#pragma unroll
    for (int o = 0; o < 21; ++o)
        integ[o] = (integ[o] - mu) * r * gamma[o] + beta[o];

    // ---- out = normed @ W_out^T + b_out   [21 -> 4]
    float o4[4];
#pragma unroll
    for (int p = 0; p < 4; ++p) {
        const float* w = W_out + p * 21;
        float acc = b_out[p];
#pragma unroll
        for (int o = 0; o < 21; ++o) acc = fmaf(integ[o], w[o], acc);
        o4[p] = acc;
    }
    *reinterpret_cast<float4*>(out + (size_t)(row0 + t) * 4) =
        make_float4(o4[0], o4[1], o4[2], o4[3]);
}

extern "C" void kernel_launch(void* const* d_in, const int* in_sizes, int n_in,
                              void* d_out, int out_size, void* d_ws, size_t ws_size,
                              hipStream_t stream) {
    const float* x     = (const float*)d_in[0];
    const float* W_in  = (const float*)d_in[1];
    const float* b_in  = (const float*)d_in[2];
    const float* Wn    = (const float*)d_in[3];
    const float* bn    = (const float*)d_in[4];
    const float* W_int = (const float*)d_in[5];
    const float* b_int = (const float*)d_in[6];
    const float* gamma = (const float*)d_in[7];
    const float* beta  = (const float*)d_in[8];
    const float* W_out = (const float*)d_in[9];
    const float* b_out = (const float*)d_in[10];
    float* out = (float*)d_out;

    const int B = in_sizes[0] / 256;          // 262144, multiple of 256
    seven_neurons_kernel<<<B / 256, 256, 0, stream>>>(
        x, W_in, b_in, Wn, bn, W_int, b_int, gamma, beta, W_out, b_out, out);
}

// Round 3
// 235.632 us; speedup vs baseline: 1.7239x; 1.7239x over previous
//
#include <hip/hip_runtime.h>

#define PHI     1.618033988749895f
#define INV_PHI 0.6180339887498949f

__device__ __forceinline__ float phi_spiral(float v) {
    // sigmoid(v/phi) * (v*phi / (1+|v|))
    float e = __expf(-v * INV_PHI);
    float s = __fdividef(1.0f, 1.0f + e);
    float g = __fdividef(v * PHI, 1.0f + fabsf(v));
    return s * g;
}

// Grid is exactly B/256 blocks (4 blocks/CU). Pin waves/EU to [4,4] so the
// register allocator gets the full 512/4 = 128 VGPR budget; peak live set
// (~105 floats in stage 2) then stays in registers instead of scratch.
__global__ __launch_bounds__(256)
__attribute__((amdgpu_waves_per_eu(4, 4)))
void seven_neurons_kernel(
    const float* __restrict__ x,
    const float* __restrict__ W_in,  const float* __restrict__ b_in,
    const float* __restrict__ Wn,    const float* __restrict__ bn,
    const float* __restrict__ W_int, const float* __restrict__ b_int,
    const float* __restrict__ gamma, const float* __restrict__ beta,
    const float* __restrict__ W_out, const float* __restrict__ b_out,
    float* __restrict__ out)
{
    const int row = blockIdx.x * 256 + threadIdx.x;
    const float* xr = x + (size_t)row * 256;

    // ---- stage 1: h = spiral(x @ W_in^T + b_in)   [256 -> 49]
    float h[49];
#pragma unroll
    for (int j = 0; j < 49; ++j) h[j] = b_in[j];     // uniform -> s_load

#pragma unroll 1
    for (int c = 0; c < 256; c += 16) {
        float xv[16];
#pragma unroll
        for (int u = 0; u < 4; ++u) {
            const float4 t = *reinterpret_cast<const float4*>(xr + c + u * 4);
            xv[u * 4 + 0] = t.x; xv[u * 4 + 1] = t.y;
            xv[u * 4 + 2] = t.z; xv[u * 4 + 3] = t.w;
        }
#pragma unroll
        for (int j = 0; j < 49; ++j) {
            const float* w = W_in + j * 256 + c;     // wave-uniform -> s_load
            float acc = h[j];
#pragma unroll
            for (int u = 0; u < 16; ++u) acc = fmaf(xv[u], w[u], acc);
            h[j] = acc;
        }
    }
#pragma unroll
    for (int j = 0; j < 49; ++j) h[j] = phi_spiral(h[j]);

    // ---- stage 2: combined = spiral(einsum('bi,khi->bkh'))   [49 -> 49]
    float comb[49];
#pragma unroll 1
    for (int m = 0; m < 49; ++m) {
        const float* w = Wn + m * 49;
        float acc = bn[m];
#pragma unroll
        for (int i = 0; i < 49; ++i) acc = fmaf(h[i], w[i], acc);
        comb[m] = phi_spiral(acc);
    }

    // ---- stage 3: integrated = spiral(comb @ W_int^T + b_int)   [49 -> 21]
    float integ[21];
#pragma unroll 1
    for (int o = 0; o < 21; ++o) {
        const float* w = W_int + o * 49;
        float acc = b_int[o];
#pragma unroll
        for (int i = 0; i < 49; ++i) acc = fmaf(comb[i], w[i], acc);
        integ[o] = phi_spiral(acc);
    }

    // ---- LayerNorm over 21 (eps = 1e-5)
    float mu = 0.f;
#pragma unroll
    for (int o = 0; o < 21; ++o) mu += integ[o];
    mu *= (1.0f / 21.0f);
    float var = 0.f;
#pragma unroll
    for (int o = 0; o < 21; ++o) { float d = integ[o] - mu; var = fmaf(d, d, var); }
    var *= (1.0f / 21.0f);
    const float r = rsqrtf(var + 1e-5f);
#pragma unroll
    for (int o = 0; o < 21; ++o)
        integ[o] = (integ[o] - mu) * r * gamma[o] + beta[o];

    // ---- out = normed @ W_out^T + b_out   [21 -> 4]
    float o4[4];
#pragma unroll
    for (int p = 0; p < 4; ++p) {
        const float* w = W_out + p * 21;
        float acc = b_out[p];
#pragma unroll
        for (int o = 0; o < 21; ++o) acc = fmaf(integ[o], w[o], acc);
        o4[p] = acc;
    }
    *reinterpret_cast<float4*>(out + (size_t)row * 4) =
        make_float4(o4[0], o4[1], o4[2], o4[3]);
}

extern "C" void kernel_launch(void* const* d_in, const int* in_sizes, int n_in,
                              void* d_out, int out_size, void* d_ws, size_t ws_size,
                              hipStream_t stream) {
    const float* x     = (const float*)d_in[0];
    const float* W_in  = (const float*)d_in[1];
    const float* b_in  = (const float*)d_in[2];
    const float* Wn    = (const float*)d_in[3];
    const float* bn    = (const float*)d_in[4];
    const float* W_int = (const float*)d_in[5];
    const float* b_int = (const float*)d_in[6];
    const float* gamma = (const float*)d_in[7];
    const float* beta  = (const float*)d_in[8];
    const float* W_out = (const float*)d_in[9];
    const float* b_out = (const float*)d_in[10];
    float* out = (float*)d_out;

    const int B = in_sizes[0] / 256;          // 262144, multiple of 256
    seven_neurons_kernel<<<B / 256, 256, 0, stream>>>(
        x, W_in, b_in, Wn, bn, W_int, b_int, gamma, beta, W_out, b_out, out);
}

// Round 4
// 210.130 us; speedup vs baseline: 1.9331x; 1.1214x over previous
//
#include <hip/hip_runtime.h>

#define PHI     1.618033988749895f
#define INV_PHI 0.6180339887498949f

__device__ __forceinline__ float phi_spiral(float v) {
    // sigmoid(v/phi) * (v*phi / (1+|v|))
    float e = __expf(-v * INV_PHI);
    float s = __fdividef(1.0f, 1.0f + e);
    float g = __fdividef(v * PHI, 1.0f + fabsf(v));
    return s * g;
}

// Grid is exactly B/256 blocks (4 blocks/CU => 4 waves/EU). waves_per_eu(4,4)
// gives the allocator the full 512/4 = 128 VGPR budget.
// CRITICAL (rule #20): stage-2/3 loops are FULLY unrolled so comb[]/integ[]
// are only ever indexed by compile-time constants -> register-resident, no
// scratch. R3's `#pragma unroll 1` versions put comb[49] in local memory
// (VGPR=52, WRITE_SIZE 54 MB of spill traffic).
__global__ __launch_bounds__(256)
__attribute__((amdgpu_waves_per_eu(4, 4)))
void seven_neurons_kernel(
    const float* __restrict__ x,
    const float* __restrict__ W_in,  const float* __restrict__ b_in,
    const float* __restrict__ Wn,    const float* __restrict__ bn,
    const float* __restrict__ W_int, const float* __restrict__ b_int,
    const float* __restrict__ gamma, const float* __restrict__ beta,
    const float* __restrict__ W_out, const float* __restrict__ b_out,
    float* __restrict__ out)
{
    const int row = blockIdx.x * 256 + threadIdx.x;
    const float* xr = x + (size_t)row * 256;

    // ---- stage 1: h = spiral(x @ W_in^T + b_in)   [256 -> 49]
    float h[49];
#pragma unroll
    for (int j = 0; j < 49; ++j) h[j] = b_in[j];     // uniform -> s_load

#pragma unroll 1
    for (int c = 0; c < 256; c += 16) {
        float xv[16];
#pragma unroll
        for (int u = 0; u < 4; ++u) {
            const float4 t = *reinterpret_cast<const float4*>(xr + c + u * 4);
            xv[u * 4 + 0] = t.x; xv[u * 4 + 1] = t.y;
            xv[u * 4 + 2] = t.z; xv[u * 4 + 3] = t.w;
        }
#pragma unroll
        for (int j = 0; j < 49; ++j) {
            const float* w = W_in + j * 256 + c;     // wave-uniform -> s_load
            float acc = h[j];
#pragma unroll
            for (int u = 0; u < 16; ++u) acc = fmaf(xv[u], w[u], acc);
            h[j] = acc;
        }
    }
#pragma unroll
    for (int j = 0; j < 49; ++j) h[j] = phi_spiral(h[j]);

    // ---- stage 2: combined = spiral(einsum('bi,khi->bkh'))   [49 -> 49]
    float comb[49];
#pragma unroll
    for (int m = 0; m < 49; ++m) {                   // FULL unroll: static idx
        const float* w = Wn + m * 49;
        float acc = bn[m];
#pragma unroll
        for (int i = 0; i < 49; ++i) acc = fmaf(h[i], w[i], acc);
        comb[m] = phi_spiral(acc);
    }

    // ---- stage 3: integrated = spiral(comb @ W_int^T + b_int)   [49 -> 21]
    float integ[21];
#pragma unroll
    for (int o = 0; o < 21; ++o) {                   // FULL unroll: static idx
        const float* w = W_int + o * 49;
        float acc = b_int[o];
#pragma unroll
        for (int i = 0; i < 49; ++i) acc = fmaf(comb[i], w[i], acc);
        integ[o] = phi_spiral(acc);
    }

    // ---- LayerNorm over 21 (eps = 1e-5)
    float mu = 0.f;
#pragma unroll
    for (int o = 0; o < 21; ++o) mu += integ[o];
    mu *= (1.0f / 21.0f);
    float var = 0.f;
#pragma unroll
    for (int o = 0; o < 21; ++o) { float d = integ[o] - mu; var = fmaf(d, d, var); }
    var *= (1.0f / 21.0f);
    const float r = rsqrtf(var + 1e-5f);
#pragma unroll
    for (int o = 0; o < 21; ++o)
        integ[o] = (integ[o] - mu) * r * gamma[o] + beta[o];

    // ---- out = normed @ W_out^T + b_out   [21 -> 4]
    float o4[4];
#pragma unroll
    for (int p = 0; p < 4; ++p) {
        const float* w = W_out + p * 21;
        float acc = b_out[p];
#pragma unroll
        for (int o = 0; o < 21; ++o) acc = fmaf(integ[o], w[o], acc);
        o4[p] = acc;
    }
    *reinterpret_cast<float4*>(out + (size_t)row * 4) =
        make_float4(o4[0], o4[1], o4[2], o4[3]);
}

extern "C" void kernel_launch(void* const* d_in, const int* in_sizes, int n_in,
                              void* d_out, int out_size, void* d_ws, size_t ws_size,
                              hipStream_t stream) {
    const float* x     = (const float*)d_in[0];
    const float* W_in  = (const float*)d_in[1];
    const float* b_in  = (const float*)d_in[2];
    const float* Wn    = (const float*)d_in[3];
    const float* bn    = (const float*)d_in[4];
    const float* W_int = (const float*)d_in[5];
    const float* b_int = (const float*)d_in[6];
    const float* gamma = (const float*)d_in[7];
    const float* beta  = (const float*)d_in[8];
    const float* W_out = (const float*)d_in[9];
    const float* b_out = (const float*)d_in[10];
    float* out = (float*)d_out;

    const int B = in_sizes[0] / 256;          // 262144, multiple of 256
    seven_neurons_kernel<<<B / 256, 256, 0, stream>>>(
        x, W_in, b_in, Wn, bn, W_int, b_int, gamma, beta, W_out, b_out, out);
}